// Round 7
// baseline (956.311 us; speedup 1.0000x reference)
//
#include <hip/hip_runtime.h>
#include <math.h>

// ROOT-CAUSE FIX (R6 post-mortem): all prior rounds quarter-staged 64x64 LDS
// tiles (lr = tid>>4 covers rows 0..15 only; rows 16..63 were uninitialized
// LDS garbage). Every staging below covers all 64 rows via rr-loops or
// row-per-lane loops. fp32 I/O per the reference contract. Host branches on
// ws_size: S1 (ws >= 589,824 B) stores K/V in d_out's high half; S3 fallback
// (ws >= 294,912 B) recomputes K/V inside attention, quarter-processing.
#define BATCH 2
#define C 64
#define HH 48
#define WW 48
#define NTOK 2304
#define NHALF 1152
#define HEADS 8

typedef unsigned short bf16_t;
__device__ __forceinline__ bf16_t f2bf(float f) {
    unsigned int u = __float_as_uint(f);
    u = (u + 0x7fffu + ((u >> 16) & 1u)) >> 16;   // RNE
    return (bf16_t)u;
}
__device__ __forceinline__ unsigned pack2(float a, float b) {
    return (unsigned)f2bf(a) | ((unsigned)f2bf(b) << 16);
}
__device__ __forceinline__ float4 ld_bf4(const bf16_t* p) {
    uint2 v = *(const uint2*)p;
    float4 r;
    r.x = __uint_as_float(v.x << 16); r.y = __uint_as_float(v.x & 0xffff0000u);
    r.z = __uint_as_float(v.y << 16); r.w = __uint_as_float(v.y & 0xffff0000u);
    return r;
}

// Stage one token-row of X (64 channels) into LDS. strm 0: rgb transpose
// gather. strm 1: conv1x1+ReLU+bilinear x2 (half-pixel; clamp == jax edge
// renormalization for 24->48).
__device__ __forceinline__ void stage_x_row(
    float* xrow, const float* rgb, const float* dep,
    const float* w_exp, const float* b_exp,
    int b, int n, int strm, int c0, int cstep)
{
    int wi = n / HH, hi = n % HH;
    if (strm == 0) {
        const float* base = rgb + (size_t)b * C * NTOK + (size_t)hi * WW + wi;
        for (int c = c0; c < 64; c += cstep)
            xrow[c] = base[(size_t)c * NTOK];
    } else {
        float cy = 0.5f * hi - 0.25f, cx = 0.5f * wi - 0.25f;
        float fy0 = floorf(cy), fx0 = floorf(cx);
        float fy = cy - fy0, fx = cx - fx0;
        int y0 = max((int)fy0, 0), x0 = max((int)fx0, 0);
        int y1 = min((int)fy0 + 1, 23), x1 = min((int)fx0 + 1, 23);
        const float* dp = dep + b * 576;
        float d00 = dp[y0*24 + x0], d01 = dp[y0*24 + x1];
        float d10 = dp[y1*24 + x0], d11 = dp[y1*24 + x1];
        for (int c = c0; c < 64; c += cstep) {
            float w = w_exp[c], bb = b_exp[c];
            float r00 = fmaxf(w*d00 + bb, 0.f), r01 = fmaxf(w*d01 + bb, 0.f);
            float r10 = fmaxf(w*d10 + bb, 0.f), r11 = fmaxf(w*d11 + bb, 0.f);
            xrow[c] = (1.f-fy)*((1.f-fx)*r00 + fx*r01) + fy*((1.f-fx)*r10 + fx*r11);
        }
    }
}

// ---------------------------------------------------------------------------
// S1 Kernel: prep + K/V GEMMs, one (batch, stream). grid(36), 256 thr.
// K[n*64+o], V[n*64+o] bf16 (n batch-local) into d_out high half.
// ---------------------------------------------------------------------------
__global__ __launch_bounds__(256) void kv_kernel(
    const float* __restrict__ rgb, const float* __restrict__ dep,
    const float* __restrict__ w_exp, const float* __restrict__ b_exp,
    const float* __restrict__ wk, const float* __restrict__ wv,
    bf16_t* __restrict__ K, bf16_t* __restrict__ V, int b, int strm)
{
    int tile = blockIdx.x;   // 0..35
    __shared__ float Xs[64][68];
    __shared__ float Ws[64][68];
    int tid = threadIdx.x;
    {   // full 64 rows: r = tid&63, 16 channels each
        int r = tid & 63, c0 = tid >> 6;
        stage_x_row(&Xs[r][0], rgb, dep, w_exp, b_exp, b, tile*64 + r, strm, c0, 4);
    }
    int sr = tid >> 4, sc = (tid & 15) * 4;
    int ty = tid >> 4, tx = tid & 15;

    #pragma unroll
    for (int m = 0; m < 2; ++m) {
        const float* W = (m == 0) ? wk : wv;
        __syncthreads();   // Xs ready (m=0) / prior GEMM done with Ws (m=1)
        #pragma unroll
        for (int rr = 0; rr < 4; ++rr) {           // FULL 64 rows
            int r = rr*16 + sr;
            *(float4*)&Ws[r][sc] = *(const float4*)&W[r*64 + sc];
        }
        __syncthreads();

        float acc[4][4] = {};
        #pragma unroll
        for (int k = 0; k < 64; k += 4) {
            float4 xv[4], wv4[4];
            #pragma unroll
            for (int i = 0; i < 4; ++i) xv[i] = *(const float4*)&Xs[4*ty + i][k];
            #pragma unroll
            for (int j = 0; j < 4; ++j) wv4[j] = *(const float4*)&Ws[tx + 16*j][k];
            #pragma unroll
            for (int i = 0; i < 4; ++i)
                #pragma unroll
                for (int j = 0; j < 4; ++j)
                    acc[i][j] += xv[i].x*wv4[j].x + xv[i].y*wv4[j].y + xv[i].z*wv4[j].z + xv[i].w*wv4[j].w;
        }
        bf16_t* O = (m == 0 ? K : V) + (size_t)tile * 4096;
        #pragma unroll
        for (int i = 0; i < 4; ++i)
            #pragma unroll
            for (int j = 0; j < 4; ++j)
                O[(4*ty + i)*64 + tx + 16*j] = f2bf(acc[i][j]);
    }
}

// ---------------------------------------------------------------------------
// S1 Kernel: flash attention from stored K/V. grid(36,8), 64 thr.
// Q on-the-fly. which==0: Q rgb vs depth K/V; which==1: Q depth vs rgb K/V.
// AO[n*64+8h] bf16, n batch-local.
// ---------------------------------------------------------------------------
#define TK 384
__global__ __launch_bounds__(64) void attn_kv_kernel(
    const float* __restrict__ rgb, const float* __restrict__ dep,
    const float* __restrict__ w_exp, const float* __restrict__ b_exp,
    const float* __restrict__ wq,
    const bf16_t* __restrict__ K, const bf16_t* __restrict__ V,
    bf16_t* __restrict__ AO, int b, int which)
{
    int qt = blockIdx.x;
    int h  = blockIdx.y;
    __shared__ float Xs[64][68];
    __shared__ float Wqs[8][64];
    __shared__ __align__(16) float Ks[TK * 8];
    __shared__ __align__(16) float Vs[TK * 8];

    int t = threadIdx.x;
    int n = qt * 64 + t;
    stage_x_row(&Xs[t][0], rgb, dep, w_exp, b_exp, b, n, which == 0 ? 0 : 1, 0, 1);
    #pragma unroll
    for (int d = 0; d < 8; ++d) Wqs[d][t] = wq[(8*h + d)*64 + t];  // full 8x64
    __syncthreads();

    const float sc = 0.35355339059327373f * 1.4426950408889634f; // 8^-0.5*log2e
    float q[8];
    #pragma unroll
    for (int d = 0; d < 8; ++d) {
        float s = 0.f;
        #pragma unroll 8
        for (int c = 0; c < 64; ++c) s += Xs[t][c] * Wqs[d][c];
        q[d] = s * sc;
    }

    float mrun = -INFINITY, l = 0.f;
    float acc[8] = {};

    for (int t0 = 0; t0 < NTOK; t0 += TK) {
        __syncthreads();   // prior tile reads done before overwriting Ks/Vs
        #pragma unroll
        for (int rr = 0; rr < TK / 64; ++rr) {     // full 384 rows
            int j = rr * 64 + t;
            int g = (t0 + j) * 64 + 8 * h;
            *(float4*)&Ks[j*8]     = ld_bf4(&K[g]);
            *(float4*)&Ks[j*8 + 4] = ld_bf4(&K[g + 4]);
            *(float4*)&Vs[j*8]     = ld_bf4(&V[g]);
            *(float4*)&Vs[j*8 + 4] = ld_bf4(&V[g + 4]);
        }
        __syncthreads();

        for (int g8 = 0; g8 < TK / 8; ++g8) {
            float s[8];
            #pragma unroll
            for (int u = 0; u < 8; ++u) {
                const float4 ka = *(const float4*)&Ks[(g8*8 + u)*8];
                const float4 kb = *(const float4*)&Ks[(g8*8 + u)*8 + 4];
                s[u] = q[0]*ka.x + q[1]*ka.y + q[2]*ka.z + q[3]*ka.w
                     + q[4]*kb.x + q[5]*kb.y + q[6]*kb.z + q[7]*kb.w;
            }
            float tm = fmaxf(fmaxf(fmaxf(s[0],s[1]), fmaxf(s[2],s[3])),
                             fmaxf(fmaxf(s[4],s[5]), fmaxf(s[6],s[7])));
            float mn = fmaxf(mrun, tm);
            float alpha = __builtin_amdgcn_exp2f(mrun - mn);
            float ps = 0.f;
            #pragma unroll
            for (int u = 0; u < 8; ++u) { s[u] = __builtin_amdgcn_exp2f(s[u] - mn); ps += s[u]; }
            l = l * alpha + ps;
            #pragma unroll
            for (int d = 0; d < 8; ++d) acc[d] *= alpha;
            #pragma unroll
            for (int u = 0; u < 8; ++u) {
                const float4 va = *(const float4*)&Vs[(g8*8 + u)*8];
                const float4 vb = *(const float4*)&Vs[(g8*8 + u)*8 + 4];
                acc[0] += s[u]*va.x; acc[1] += s[u]*va.y; acc[2] += s[u]*va.z; acc[3] += s[u]*va.w;
                acc[4] += s[u]*vb.x; acc[5] += s[u]*vb.y; acc[6] += s[u]*vb.z; acc[7] += s[u]*vb.w;
            }
            mrun = mn;
        }
    }
    float inv = 1.0f / l;
    uint4 o;
    o.x = pack2(acc[0]*inv, acc[1]*inv);
    o.y = pack2(acc[2]*inv, acc[3]*inv);
    o.z = pack2(acc[4]*inv, acc[5]*inv);
    o.w = pack2(acc[6]*inv, acc[7]*inv);
    *(uint4*)&AO[(size_t)n * 64 + 8 * h] = o;
}

// ---------------------------------------------------------------------------
// S3 Kernel: flash attention with per-tile K/V RECOMPUTE (zero d_out scratch).
// grid(18,8), 64 thr. Queries [n0, n0+1152). AO[(n-n0)*64+8h] bf16.
// ---------------------------------------------------------------------------
__global__ __launch_bounds__(64) void attn_rc_kernel(
    const float* __restrict__ rgb, const float* __restrict__ dep,
    const float* __restrict__ w_exp, const float* __restrict__ b_exp,
    const float* __restrict__ wq, const float* __restrict__ wk, const float* __restrict__ wv,
    bf16_t* __restrict__ AO, int b, int which, int n0)
{
    int qt = blockIdx.x;
    int h  = blockIdx.y;
    __shared__ float X[64][68];
    __shared__ float Wq8[8][64], Wk8[8][64], Wv8[8][64];
    __shared__ __align__(16) float Kt[64][8];
    __shared__ __align__(16) float Vt[64][8];

    int t = threadIdx.x;
    int qstrm = (which == 0) ? 0 : 1;
    int kstrm = 1 - qstrm;
    #pragma unroll
    for (int d = 0; d < 8; ++d) {
        Wq8[d][t] = wq[(8*h + d)*64 + t];
        Wk8[d][t] = wk[(8*h + d)*64 + t];
        Wv8[d][t] = wv[(8*h + d)*64 + t];
    }
    int n = n0 + qt * 64 + t;
    stage_x_row(&X[t][0], rgb, dep, w_exp, b_exp, b, n, qstrm, 0, 1);
    __syncthreads();

    const float sc = 0.35355339059327373f * 1.4426950408889634f;
    float q[8];
    #pragma unroll
    for (int d = 0; d < 8; ++d) {
        float s = 0.f;
        #pragma unroll 8
        for (int c = 0; c < 64; ++c) s += X[t][c] * Wq8[d][c];
        q[d] = s * sc;
    }

    float mrun = -INFINITY, l = 0.f;
    float acc[8] = {};

    for (int kt = 0; kt < 36; ++kt) {
        __syncthreads();   // prior Kt/Vt reads done; X (own-row) safe
        stage_x_row(&X[t][0], rgb, dep, w_exp, b_exp, b, kt*64 + t, kstrm, 0, 1);
        // own-row read of X: no barrier needed before Kt/Vt compute
        #pragma unroll
        for (int d = 0; d < 8; ++d) {
            float kk = 0.f, vv = 0.f;
            #pragma unroll 8
            for (int c = 0; c < 64; ++c) {
                float x = X[t][c];
                kk += x * Wk8[d][c];
                vv += x * Wv8[d][c];
            }
            Kt[t][d] = kk;
            Vt[t][d] = vv;
        }
        __syncthreads();   // Kt/Vt complete before cross-lane reads

        for (int g8 = 0; g8 < 8; ++g8) {
            float s[8];
            #pragma unroll
            for (int u = 0; u < 8; ++u) {
                const float4 ka = *(const float4*)&Kt[g8*8 + u][0];
                const float4 kb = *(const float4*)&Kt[g8*8 + u][4];
                s[u] = q[0]*ka.x + q[1]*ka.y + q[2]*ka.z + q[3]*ka.w
                     + q[4]*kb.x + q[5]*kb.y + q[6]*kb.z + q[7]*kb.w;
            }
            float tm = fmaxf(fmaxf(fmaxf(s[0],s[1]), fmaxf(s[2],s[3])),
                             fmaxf(fmaxf(s[4],s[5]), fmaxf(s[6],s[7])));
            float mn = fmaxf(mrun, tm);
            float alpha = __builtin_amdgcn_exp2f(mrun - mn);
            float ps = 0.f;
            #pragma unroll
            for (int u = 0; u < 8; ++u) { s[u] = __builtin_amdgcn_exp2f(s[u] - mn); ps += s[u]; }
            l = l * alpha + ps;
            #pragma unroll
            for (int d = 0; d < 8; ++d) acc[d] *= alpha;
            #pragma unroll
            for (int u = 0; u < 8; ++u) {
                const float4 va = *(const float4*)&Vt[g8*8 + u][0];
                const float4 vb = *(const float4*)&Vt[g8*8 + u][4];
                acc[0] += s[u]*va.x; acc[1] += s[u]*va.y; acc[2] += s[u]*va.z; acc[3] += s[u]*va.w;
                acc[4] += s[u]*vb.x; acc[5] += s[u]*vb.y; acc[6] += s[u]*vb.z; acc[7] += s[u]*vb.w;
            }
            mrun = mn;
        }
    }
    float inv = 1.0f / l;
    uint4 o;
    o.x = pack2(acc[0]*inv, acc[1]*inv);
    o.y = pack2(acc[2]*inv, acc[3]*inv);
    o.z = pack2(acc[4]*inv, acc[5]*inv);
    o.w = pack2(acc[6]*inv, acc[7]*inv);
    *(uint4*)&AO[(size_t)(n - n0) * 64 + 8 * h] = o;
}

// ---------------------------------------------------------------------------
// Fused proj(+bias) -> compress(+bias) -> exact GELU -> fp32 store.
// grid(nq/64), 256 thr. 3 rotating 64x68 buffers (52 KB LDS). Token rows
// [n0, n0+grid*64) of batch b; AOr/AOd indexed by local row.
// ---------------------------------------------------------------------------
__global__ __launch_bounds__(256) void projcomp_kernel(
    const bf16_t* __restrict__ AOr, const bf16_t* __restrict__ AOd,
    const float* __restrict__ w_rp, const float* __restrict__ b_rp,
    const float* __restrict__ w_dp, const float* __restrict__ b_dp,
    const float* __restrict__ w_comp, const float* __restrict__ b_comp,
    float* __restrict__ out, int b, int n0)
{
    int tile = blockIdx.x;
    __shared__ float A[64][68];
    __shared__ float Bf[64][68];
    __shared__ float Pf[64][68];
    int tid = threadIdx.x;
    int sr = tid >> 4, sc = (tid & 15) * 4;
    int ty = tid >> 4, tx = tid & 15;
    float G[4][4] = {};

    #pragma unroll
    for (int half = 0; half < 2; ++half) {
        const bf16_t* AOx = half ? AOd : AOr;
        const float* Wp   = half ? w_dp : w_rp;
        const float* bp   = half ? b_dp : b_rp;
        // stage AO tile + proj weight (FULL 64 rows)
        #pragma unroll
        for (int rr = 0; rr < 4; ++rr) {
            int r = rr*16 + sr;
            *(float4*)&A[r][sc]  = ld_bf4(&AOx[((size_t)tile*64 + r)*64 + sc]);
            *(float4*)&Bf[r][sc] = *(const float4*)&Wp[r*64 + sc];
        }
        __syncthreads();
        float acc[4][4] = {};
        #pragma unroll
        for (int k = 0; k < 64; k += 4) {
            float4 xv[4], wv[4];
            #pragma unroll
            for (int i = 0; i < 4; ++i) xv[i] = *(const float4*)&A[4*ty + i][k];
            #pragma unroll
            for (int j = 0; j < 4; ++j) wv[j] = *(const float4*)&Bf[tx + 16*j][k];
            #pragma unroll
            for (int i = 0; i < 4; ++i)
                #pragma unroll
                for (int j = 0; j < 4; ++j)
                    acc[i][j] += xv[i].x*wv[j].x + xv[i].y*wv[j].y + xv[i].z*wv[j].z + xv[i].w*wv[j].w;
        }
        __syncthreads();   // GEMM reads of A/Bf done before Pf write + Bf restage
        #pragma unroll
        for (int j = 0; j < 4; ++j) {
            float bj = bp[tx + 16*j];
            #pragma unroll
            for (int i = 0; i < 4; ++i)
                Pf[4*ty + i][tx + 16*j] = acc[i][j] + bj;
        }
        #pragma unroll
        for (int rr = 0; rr < 4; ++rr) {   // w_comp half (FULL 64 rows)
            int r = rr*16 + sr;
            *(float4*)&Bf[r][sc] = *(const float4*)&w_comp[r*128 + half*64 + sc];
        }
        __syncthreads();
        #pragma unroll
        for (int k = 0; k < 64; k += 4) {
            float4 xv[4], wv[4];
            #pragma unroll
            for (int i = 0; i < 4; ++i) xv[i] = *(const float4*)&Pf[4*ty + i][k];
            #pragma unroll
            for (int j = 0; j < 4; ++j) wv[j] = *(const float4*)&Bf[tx + 16*j][k];
            #pragma unroll
            for (int i = 0; i < 4; ++i)
                #pragma unroll
                for (int j = 0; j < 4; ++j)
                    G[i][j] += xv[i].x*wv[j].x + xv[i].y*wv[j].y + xv[i].z*wv[j].z + xv[i].w*wv[j].w;
        }
        __syncthreads();   // Pf/Bf reads done before next half overwrites
    }

    #pragma unroll
    for (int j = 0; j < 4; ++j) {
        int o = tx + 16*j;
        float bj = b_comp[o];
        #pragma unroll
        for (int i = 0; i < 4; ++i) {
            int n = n0 + tile*64 + 4*ty + i;
            int wi = n / HH, hi = n % HH;
            float x = G[i][j] + bj;
            float g = 0.5f * x * (1.0f + erff(x * 0.70710678118654752f));
            out[((b*C + o)*WW + wi)*HH + hi] = g;
        }
    }
}

// ---------------------------------------------------------------------------
extern "C" void kernel_launch(void* const* d_in, const int* in_sizes, int n_in,
                              void* d_out, int out_size, void* d_ws, size_t ws_size,
                              hipStream_t stream) {
    const float* rgb_fea = (const float*)d_in[0];
    const float* depth   = (const float*)d_in[1];
    const float* w_exp   = (const float*)d_in[2];
    const float* b_exp   = (const float*)d_in[3];
    const float* w_rq    = (const float*)d_in[4];
    const float* w_rk    = (const float*)d_in[5];
    const float* w_rv    = (const float*)d_in[6];
    const float* w_dq    = (const float*)d_in[7];
    const float* w_dk    = (const float*)d_in[8];
    const float* w_dv    = (const float*)d_in[9];
    const float* w_rp    = (const float*)d_in[10];
    const float* b_rp    = (const float*)d_in[11];
    const float* w_dp    = (const float*)d_in[12];
    const float* b_dp    = (const float*)d_in[13];
    const float* w_comp  = (const float*)d_in[14];
    const float* b_comp  = (const float*)d_in[15];
    float* out = (float*)d_out;

    if (ws_size >= 589824) {
        // S1: K/V bf16 in d_out HIGH half [589824, 1179648) — dead before any
        // final writes land there (batch-0 out -> LOW; batch-1 out -> HIGH
        // only after its K/V is consumed). AO bf16 in ws (589,824 B).
        bf16_t* Kb  = (bf16_t*)((float*)d_out + 147456);
        bf16_t* Vb  = Kb + 147456;
        bf16_t* AOr = (bf16_t*)d_ws;
        bf16_t* AOd = AOr + 147456;
        for (int b = 0; b < BATCH; ++b) {
            kv_kernel<<<dim3(36), dim3(256), 0, stream>>>(
                rgb_fea, depth, w_exp, b_exp, w_dk, w_dv, Kb, Vb, b, 1);
            attn_kv_kernel<<<dim3(36, 8), dim3(64), 0, stream>>>(
                rgb_fea, depth, w_exp, b_exp, w_rq, Kb, Vb, AOr, b, 0);
            kv_kernel<<<dim3(36), dim3(256), 0, stream>>>(
                rgb_fea, depth, w_exp, b_exp, w_rk, w_rv, Kb, Vb, b, 0);
            attn_kv_kernel<<<dim3(36, 8), dim3(64), 0, stream>>>(
                rgb_fea, depth, w_exp, b_exp, w_dq, Kb, Vb, AOd, b, 1);
            projcomp_kernel<<<dim3(36), dim3(256), 0, stream>>>(
                AOr, AOd, w_rp, b_rp, w_dp, b_dp, w_comp, b_comp, out, b, 0);
        }
    } else {
        // S3: zero d_out scratch; attention recomputes K/V per tile.
        // ws usage = 294,912 B (AO halves).
        bf16_t* AOr = (bf16_t*)d_ws;
        bf16_t* AOd = AOr + 73728;
        for (int b = 0; b < BATCH; ++b) {
            for (int H = 0; H < 2; ++H) {
                int n0 = H * NHALF;
                attn_rc_kernel<<<dim3(18, 8), dim3(64), 0, stream>>>(
                    rgb_fea, depth, w_exp, b_exp, w_rq, w_dk, w_dv, AOr, b, 0, n0);
                attn_rc_kernel<<<dim3(18, 8), dim3(64), 0, stream>>>(
                    rgb_fea, depth, w_exp, b_exp, w_dq, w_rk, w_rv, AOd, b, 1, n0);
                projcomp_kernel<<<dim3(18), dim3(256), 0, stream>>>(
                    AOr, AOd, w_rp, b_rp, w_dp, b_dp, w_comp, b_comp, out, b, n0);
            }
        }
    }
}

// Round 8
// 812.457 us; speedup vs baseline: 1.1771x; 1.1771x over previous
//
#include <hip/hip_runtime.h>
#include <math.h>

// R7: passed at 956us. Counters: 4x attn_kv at 166us = 70% of runtime,
// Occupancy 3.3%, VALUBusy 17.7% -> single-wave blocks are latency-bound.
// R8: split-K flash attention, 4 waves/block (wave w owns keys [576w,576w+576)),
// LDS partial merge. kv split into grid(36,2). Schedule/buffers unchanged.
#define BATCH 2
#define C 64
#define HH 48
#define WW 48
#define NTOK 2304
#define NHALF 1152
#define HEADS 8

typedef unsigned short bf16_t;
__device__ __forceinline__ bf16_t f2bf(float f) {
    unsigned int u = __float_as_uint(f);
    u = (u + 0x7fffu + ((u >> 16) & 1u)) >> 16;   // RNE
    return (bf16_t)u;
}
__device__ __forceinline__ unsigned pack2(float a, float b) {
    return (unsigned)f2bf(a) | ((unsigned)f2bf(b) << 16);
}
__device__ __forceinline__ float4 ld_bf4(const bf16_t* p) {
    uint2 v = *(const uint2*)p;
    float4 r;
    r.x = __uint_as_float(v.x << 16); r.y = __uint_as_float(v.x & 0xffff0000u);
    r.z = __uint_as_float(v.y << 16); r.w = __uint_as_float(v.y & 0xffff0000u);
    return r;
}

// Stage one token-row of X (64 channels, subset c0::cstep) into LDS row.
// strm 0: rgb transpose gather. strm 1: conv1x1+ReLU+bilinear x2 (half-pixel;
// clamp == jax edge renormalization for 24->48).
__device__ __forceinline__ void stage_x_row(
    float* xrow, const float* rgb, const float* dep,
    const float* w_exp, const float* b_exp,
    int b, int n, int strm, int c0, int cstep)
{
    int wi = n / HH, hi = n % HH;
    if (strm == 0) {
        const float* base = rgb + (size_t)b * C * NTOK + (size_t)hi * WW + wi;
        for (int c = c0; c < 64; c += cstep)
            xrow[c] = base[(size_t)c * NTOK];
    } else {
        float cy = 0.5f * hi - 0.25f, cx = 0.5f * wi - 0.25f;
        float fy0 = floorf(cy), fx0 = floorf(cx);
        float fy = cy - fy0, fx = cx - fx0;
        int y0 = max((int)fy0, 0), x0 = max((int)fx0, 0);
        int y1 = min((int)fy0 + 1, 23), x1 = min((int)fx0 + 1, 23);
        const float* dp = dep + b * 576;
        float d00 = dp[y0*24 + x0], d01 = dp[y0*24 + x1];
        float d10 = dp[y1*24 + x0], d11 = dp[y1*24 + x1];
        for (int c = c0; c < 64; c += cstep) {
            float w = w_exp[c], bb = b_exp[c];
            float r00 = fmaxf(w*d00 + bb, 0.f), r01 = fmaxf(w*d01 + bb, 0.f);
            float r10 = fmaxf(w*d10 + bb, 0.f), r11 = fmaxf(w*d11 + bb, 0.f);
            xrow[c] = (1.f-fy)*((1.f-fx)*r00 + fx*r01) + fy*((1.f-fx)*r10 + fx*r11);
        }
    }
}

// ---------------------------------------------------------------------------
// S1 Kernel: prep + one of {K,V} GEMM. grid(36, 2): tile, m(0=K,1=V). 256 thr.
// O[n*64+o] bf16 (n batch-local) into d_out high half.
// ---------------------------------------------------------------------------
__global__ __launch_bounds__(256) void kv_kernel(
    const float* __restrict__ rgb, const float* __restrict__ dep,
    const float* __restrict__ w_exp, const float* __restrict__ b_exp,
    const float* __restrict__ wk, const float* __restrict__ wv,
    bf16_t* __restrict__ K, bf16_t* __restrict__ V, int b, int strm)
{
    int tile = blockIdx.x;   // 0..35
    int m    = blockIdx.y;   // 0=K, 1=V
    const float* W = (m == 0) ? wk : wv;
    __shared__ float Xs[64][68];
    __shared__ float Ws[64][68];
    int tid = threadIdx.x;
    {   // full 64 rows: r = tid&63, 16 channels each
        int r = tid & 63, c0 = tid >> 6;
        stage_x_row(&Xs[r][0], rgb, dep, w_exp, b_exp, b, tile*64 + r, strm, c0, 4);
    }
    int sr = tid >> 4, sc = (tid & 15) * 4;
    #pragma unroll
    for (int rr = 0; rr < 4; ++rr) {           // FULL 64 rows
        int r = rr*16 + sr;
        *(float4*)&Ws[r][sc] = *(const float4*)&W[r*64 + sc];
    }
    __syncthreads();

    int ty = tid >> 4, tx = tid & 15;
    float acc[4][4] = {};
    #pragma unroll
    for (int k = 0; k < 64; k += 4) {
        float4 xv[4], wv4[4];
        #pragma unroll
        for (int i = 0; i < 4; ++i) xv[i] = *(const float4*)&Xs[4*ty + i][k];
        #pragma unroll
        for (int j = 0; j < 4; ++j) wv4[j] = *(const float4*)&Ws[tx + 16*j][k];
        #pragma unroll
        for (int i = 0; i < 4; ++i)
            #pragma unroll
            for (int j = 0; j < 4; ++j)
                acc[i][j] += xv[i].x*wv4[j].x + xv[i].y*wv4[j].y + xv[i].z*wv4[j].z + xv[i].w*wv4[j].w;
    }
    bf16_t* O = (m == 0 ? K : V) + (size_t)tile * 4096;
    #pragma unroll
    for (int i = 0; i < 4; ++i)
        #pragma unroll
        for (int j = 0; j < 4; ++j)
            O[(4*ty + i)*64 + tx + 16*j] = f2bf(acc[i][j]);
}

// ---------------------------------------------------------------------------
// S1 Kernel: split-K flash attention. grid(36, 8), 256 thr (4 waves).
// Wave w handles keys [576w, 576w+576) for queries [qt*64, qt*64+64); each
// wave stages 64-key K/V tiles into its own LDS quadrant (no cross-wave
// staging dependency). Partials (m,l,acc8) merged via LDS (exact).
// Q on-the-fly from the query-side stream. AO[n*64+8h] bf16, n batch-local.
// ---------------------------------------------------------------------------
__global__ __launch_bounds__(256) void attn_kv_kernel(
    const float* __restrict__ rgb, const float* __restrict__ dep,
    const float* __restrict__ w_exp, const float* __restrict__ b_exp,
    const float* __restrict__ wq,
    const bf16_t* __restrict__ K, const bf16_t* __restrict__ V,
    bf16_t* __restrict__ AO, int b, int which)
{
    int qt = blockIdx.x;     // 0..35
    int h  = blockIdx.y;     // 0..7
    __shared__ float Xs[64][68];                 // X tile; reused for partials
    __shared__ float Wqs[8][64];
    __shared__ __align__(16) float Ks[4][64][8]; // per-wave quadrants
    __shared__ __align__(16) float Vs[4][64][8];

    int tid = threadIdx.x;
    int t = tid & 63;        // query lane
    int w = tid >> 6;        // wave id
    int n = qt * 64 + t;

    // stage X tile cooperatively: row t, channels {w, w+4, ...}
    stage_x_row(&Xs[t][0], rgb, dep, w_exp, b_exp, b, n, which == 0 ? 0 : 1, w, 4);
    if (w == 0) {
        #pragma unroll
        for (int d = 0; d < 8; ++d) Wqs[d][t] = wq[(8*h + d)*64 + t];
    }
    __syncthreads();

    const float sc = 0.35355339059327373f * 1.4426950408889634f; // 8^-0.5*log2e
    float q[8];
    #pragma unroll
    for (int d = 0; d < 8; ++d) {
        float s = 0.f;
        #pragma unroll 8
        for (int c = 0; c < 64; ++c) s += Xs[t][c] * Wqs[d][c];
        q[d] = s * sc;
    }

    float mrun = -INFINITY, l = 0.f;
    float acc[8] = {};

    #pragma unroll 1
    for (int st = 0; st < 9; ++st) {
        __syncthreads();   // prior tile reads done before overwriting Ks/Vs
        {
            int g = (w*576 + st*64 + t) * 64 + 8 * h;
            *(float4*)&Ks[w][t][0] = ld_bf4(&K[g]);
            *(float4*)&Ks[w][t][4] = ld_bf4(&K[g + 4]);
            *(float4*)&Vs[w][t][0] = ld_bf4(&V[g]);
            *(float4*)&Vs[w][t][4] = ld_bf4(&V[g + 4]);
        }
        __syncthreads();

        for (int g8 = 0; g8 < 8; ++g8) {
            float s[8];
            #pragma unroll
            for (int u = 0; u < 8; ++u) {
                const float4 ka = *(const float4*)&Ks[w][g8*8 + u][0];
                const float4 kb = *(const float4*)&Ks[w][g8*8 + u][4];
                s[u] = q[0]*ka.x + q[1]*ka.y + q[2]*ka.z + q[3]*ka.w
                     + q[4]*kb.x + q[5]*kb.y + q[6]*kb.z + q[7]*kb.w;
            }
            float tm = fmaxf(fmaxf(fmaxf(s[0],s[1]), fmaxf(s[2],s[3])),
                             fmaxf(fmaxf(s[4],s[5]), fmaxf(s[6],s[7])));
            float mn = fmaxf(mrun, tm);
            float alpha = __builtin_amdgcn_exp2f(mrun - mn);
            float ps = 0.f;
            #pragma unroll
            for (int u = 0; u < 8; ++u) { s[u] = __builtin_amdgcn_exp2f(s[u] - mn); ps += s[u]; }
            l = l * alpha + ps;
            #pragma unroll
            for (int d = 0; d < 8; ++d) acc[d] *= alpha;
            #pragma unroll
            for (int u = 0; u < 8; ++u) {
                const float4 va = *(const float4*)&Vs[w][g8*8 + u][0];
                const float4 vb = *(const float4*)&Vs[w][g8*8 + u][4];
                acc[0] += s[u]*va.x; acc[1] += s[u]*va.y; acc[2] += s[u]*va.z; acc[3] += s[u]*va.w;
                acc[4] += s[u]*vb.x; acc[5] += s[u]*vb.y; acc[6] += s[u]*vb.z; acc[7] += s[u]*vb.w;
            }
            mrun = mn;
        }
    }

    // merge the 4 per-wave partials (exact flash combine) via Xs scratch
    float* part = &Xs[0][0];          // need 4*64*10 = 2560 <= 4352 floats
    __syncthreads();                  // Xs no longer needed; all waves done
    {
        float* p = &part[(w*64 + t) * 10];
        p[0] = mrun; p[1] = l;
        #pragma unroll
        for (int d = 0; d < 8; ++d) p[2 + d] = acc[d];
    }
    __syncthreads();
    if (tid < 64) {
        float M = -INFINITY;
        #pragma unroll
        for (int v = 0; v < 4; ++v) M = fmaxf(M, part[(v*64 + t)*10]);
        float L = 0.f, o[8] = {};
        #pragma unroll
        for (int v = 0; v < 4; ++v) {
            const float* p = &part[(v*64 + t)*10];
            float al = __builtin_amdgcn_exp2f(p[0] - M);
            L += p[1] * al;
            #pragma unroll
            for (int d = 0; d < 8; ++d) o[d] += p[2 + d] * al;
        }
        float inv = 1.0f / L;
        uint4 ov;
        ov.x = pack2(o[0]*inv, o[1]*inv);
        ov.y = pack2(o[2]*inv, o[3]*inv);
        ov.z = pack2(o[4]*inv, o[5]*inv);
        ov.w = pack2(o[6]*inv, o[7]*inv);
        *(uint4*)&AO[(size_t)n * 64 + 8 * h] = ov;
    }
}

// ---------------------------------------------------------------------------
// S3 Kernel: flash attention with per-tile K/V RECOMPUTE (zero d_out scratch).
// grid(18,8), 64 thr. Queries [n0, n0+1152). AO[(n-n0)*64+8h] bf16.
// ---------------------------------------------------------------------------
__global__ __launch_bounds__(64) void attn_rc_kernel(
    const float* __restrict__ rgb, const float* __restrict__ dep,
    const float* __restrict__ w_exp, const float* __restrict__ b_exp,
    const float* __restrict__ wq, const float* __restrict__ wk, const float* __restrict__ wv,
    bf16_t* __restrict__ AO, int b, int which, int n0)
{
    int qt = blockIdx.x;
    int h  = blockIdx.y;
    __shared__ float X[64][68];
    __shared__ float Wq8[8][64], Wk8[8][64], Wv8[8][64];
    __shared__ __align__(16) float Kt[64][8];
    __shared__ __align__(16) float Vt[64][8];

    int t = threadIdx.x;
    int qstrm = (which == 0) ? 0 : 1;
    int kstrm = 1 - qstrm;
    #pragma unroll
    for (int d = 0; d < 8; ++d) {
        Wq8[d][t] = wq[(8*h + d)*64 + t];
        Wk8[d][t] = wk[(8*h + d)*64 + t];
        Wv8[d][t] = wv[(8*h + d)*64 + t];
    }
    int n = n0 + qt * 64 + t;
    stage_x_row(&X[t][0], rgb, dep, w_exp, b_exp, b, n, qstrm, 0, 1);
    __syncthreads();

    const float sc = 0.35355339059327373f * 1.4426950408889634f;
    float q[8];
    #pragma unroll
    for (int d = 0; d < 8; ++d) {
        float s = 0.f;
        #pragma unroll 8
        for (int c = 0; c < 64; ++c) s += X[t][c] * Wq8[d][c];
        q[d] = s * sc;
    }

    float mrun = -INFINITY, l = 0.f;
    float acc[8] = {};

    for (int kt = 0; kt < 36; ++kt) {
        __syncthreads();
        stage_x_row(&X[t][0], rgb, dep, w_exp, b_exp, b, kt*64 + t, kstrm, 0, 1);
        #pragma unroll
        for (int d = 0; d < 8; ++d) {
            float kk = 0.f, vv = 0.f;
            #pragma unroll 8
            for (int c = 0; c < 64; ++c) {
                float x = X[t][c];
                kk += x * Wk8[d][c];
                vv += x * Wv8[d][c];
            }
            Kt[t][d] = kk;
            Vt[t][d] = vv;
        }
        __syncthreads();

        for (int g8 = 0; g8 < 8; ++g8) {
            float s[8];
            #pragma unroll
            for (int u = 0; u < 8; ++u) {
                const float4 ka = *(const float4*)&Kt[g8*8 + u][0];
                const float4 kb = *(const float4*)&Kt[g8*8 + u][4];
                s[u] = q[0]*ka.x + q[1]*ka.y + q[2]*ka.z + q[3]*ka.w
                     + q[4]*kb.x + q[5]*kb.y + q[6]*kb.z + q[7]*kb.w;
            }
            float tm = fmaxf(fmaxf(fmaxf(s[0],s[1]), fmaxf(s[2],s[3])),
                             fmaxf(fmaxf(s[4],s[5]), fmaxf(s[6],s[7])));
            float mn = fmaxf(mrun, tm);
            float alpha = __builtin_amdgcn_exp2f(mrun - mn);
            float ps = 0.f;
            #pragma unroll
            for (int u = 0; u < 8; ++u) { s[u] = __builtin_amdgcn_exp2f(s[u] - mn); ps += s[u]; }
            l = l * alpha + ps;
            #pragma unroll
            for (int d = 0; d < 8; ++d) acc[d] *= alpha;
            #pragma unroll
            for (int u = 0; u < 8; ++u) {
                const float4 va = *(const float4*)&Vt[g8*8 + u][0];
                const float4 vb = *(const float4*)&Vt[g8*8 + u][4];
                acc[0] += s[u]*va.x; acc[1] += s[u]*va.y; acc[2] += s[u]*va.z; acc[3] += s[u]*va.w;
                acc[4] += s[u]*vb.x; acc[5] += s[u]*vb.y; acc[6] += s[u]*vb.z; acc[7] += s[u]*vb.w;
            }
            mrun = mn;
        }
    }
    float inv = 1.0f / l;
    uint4 o;
    o.x = pack2(acc[0]*inv, acc[1]*inv);
    o.y = pack2(acc[2]*inv, acc[3]*inv);
    o.z = pack2(acc[4]*inv, acc[5]*inv);
    o.w = pack2(acc[6]*inv, acc[7]*inv);
    *(uint4*)&AO[(size_t)(n - n0) * 64 + 8 * h] = o;
}

// ---------------------------------------------------------------------------
// Fused proj(+bias) -> compress(+bias) -> exact GELU -> fp32 store.
// grid(nq/64), 256 thr. 3 rotating 64x68 buffers. Token rows [n0, ...).
// ---------------------------------------------------------------------------
__global__ __launch_bounds__(256) void projcomp_kernel(
    const bf16_t* __restrict__ AOr, const bf16_t* __restrict__ AOd,
    const float* __restrict__ w_rp, const float* __restrict__ b_rp,
    const float* __restrict__ w_dp, const float* __restrict__ b_dp,
    const float* __restrict__ w_comp, const float* __restrict__ b_comp,
    float* __restrict__ out, int b, int n0)
{
    int tile = blockIdx.x;
    __shared__ float A[64][68];
    __shared__ float Bf[64][68];
    __shared__ float Pf[64][68];
    int tid = threadIdx.x;
    int sr = tid >> 4, sc = (tid & 15) * 4;
    int ty = tid >> 4, tx = tid & 15;
    float G[4][4] = {};

    #pragma unroll
    for (int half = 0; half < 2; ++half) {
        const bf16_t* AOx = half ? AOd : AOr;
        const float* Wp   = half ? w_dp : w_rp;
        const float* bp   = half ? b_dp : b_rp;
        #pragma unroll
        for (int rr = 0; rr < 4; ++rr) {
            int r = rr*16 + sr;
            *(float4*)&A[r][sc]  = ld_bf4(&AOx[((size_t)tile*64 + r)*64 + sc]);
            *(float4*)&Bf[r][sc] = *(const float4*)&Wp[r*64 + sc];
        }
        __syncthreads();
        float acc[4][4] = {};
        #pragma unroll
        for (int k = 0; k < 64; k += 4) {
            float4 xv[4], wv[4];
            #pragma unroll
            for (int i = 0; i < 4; ++i) xv[i] = *(const float4*)&A[4*ty + i][k];
            #pragma unroll
            for (int j = 0; j < 4; ++j) wv[j] = *(const float4*)&Bf[tx + 16*j][k];
            #pragma unroll
            for (int i = 0; i < 4; ++i)
                #pragma unroll
                for (int j = 0; j < 4; ++j)
                    acc[i][j] += xv[i].x*wv[j].x + xv[i].y*wv[j].y + xv[i].z*wv[j].z + xv[i].w*wv[j].w;
        }
        __syncthreads();
        #pragma unroll
        for (int j = 0; j < 4; ++j) {
            float bj = bp[tx + 16*j];
            #pragma unroll
            for (int i = 0; i < 4; ++i)
                Pf[4*ty + i][tx + 16*j] = acc[i][j] + bj;
        }
        #pragma unroll
        for (int rr = 0; rr < 4; ++rr) {
            int r = rr*16 + sr;
            *(float4*)&Bf[r][sc] = *(const float4*)&w_comp[r*128 + half*64 + sc];
        }
        __syncthreads();
        #pragma unroll
        for (int k = 0; k < 64; k += 4) {
            float4 xv[4], wv[4];
            #pragma unroll
            for (int i = 0; i < 4; ++i) xv[i] = *(const float4*)&Pf[4*ty + i][k];
            #pragma unroll
            for (int j = 0; j < 4; ++j) wv[j] = *(const float4*)&Bf[tx + 16*j][k];
            #pragma unroll
            for (int i = 0; i < 4; ++i)
                #pragma unroll
                for (int j = 0; j < 4; ++j)
                    G[i][j] += xv[i].x*wv[j].x + xv[i].y*wv[j].y + xv[i].z*wv[j].z + xv[i].w*wv[j].w;
        }
        __syncthreads();
    }

    #pragma unroll
    for (int j = 0; j < 4; ++j) {
        int o = tx + 16*j;
        float bj = b_comp[o];
        #pragma unroll
        for (int i = 0; i < 4; ++i) {
            int n = n0 + tile*64 + 4*ty + i;
            int wi = n / HH, hi = n % HH;
            float x = G[i][j] + bj;
            float g = 0.5f * x * (1.0f + erff(x * 0.70710678118654752f));
            out[((b*C + o)*WW + wi)*HH + hi] = g;
        }
    }
}

// ---------------------------------------------------------------------------
extern "C" void kernel_launch(void* const* d_in, const int* in_sizes, int n_in,
                              void* d_out, int out_size, void* d_ws, size_t ws_size,
                              hipStream_t stream) {
    const float* rgb_fea = (const float*)d_in[0];
    const float* depth   = (const float*)d_in[1];
    const float* w_exp   = (const float*)d_in[2];
    const float* b_exp   = (const float*)d_in[3];
    const float* w_rq    = (const float*)d_in[4];
    const float* w_rk    = (const float*)d_in[5];
    const float* w_rv    = (const float*)d_in[6];
    const float* w_dq    = (const float*)d_in[7];
    const float* w_dk    = (const float*)d_in[8];
    const float* w_dv    = (const float*)d_in[9];
    const float* w_rp    = (const float*)d_in[10];
    const float* b_rp    = (const float*)d_in[11];
    const float* w_dp    = (const float*)d_in[12];
    const float* b_dp    = (const float*)d_in[13];
    const float* w_comp  = (const float*)d_in[14];
    const float* b_comp  = (const float*)d_in[15];
    float* out = (float*)d_out;

    if (ws_size >= 589824) {
        // S1: K/V bf16 in d_out HIGH half [589824, 1179648) — dead before any
        // final writes land there. AO bf16 in ws (589,824 B).
        bf16_t* Kb  = (bf16_t*)((float*)d_out + 147456);
        bf16_t* Vb  = Kb + 147456;
        bf16_t* AOr = (bf16_t*)d_ws;
        bf16_t* AOd = AOr + 147456;
        for (int b = 0; b < BATCH; ++b) {
            kv_kernel<<<dim3(36, 2), dim3(256), 0, stream>>>(
                rgb_fea, depth, w_exp, b_exp, w_dk, w_dv, Kb, Vb, b, 1);
            attn_kv_kernel<<<dim3(36, 8), dim3(256), 0, stream>>>(
                rgb_fea, depth, w_exp, b_exp, w_rq, Kb, Vb, AOr, b, 0);
            kv_kernel<<<dim3(36, 2), dim3(256), 0, stream>>>(
                rgb_fea, depth, w_exp, b_exp, w_rk, w_rv, Kb, Vb, b, 0);
            attn_kv_kernel<<<dim3(36, 8), dim3(256), 0, stream>>>(
                rgb_fea, depth, w_exp, b_exp, w_dq, Kb, Vb, AOd, b, 1);
            projcomp_kernel<<<dim3(36), dim3(256), 0, stream>>>(
                AOr, AOd, w_rp, b_rp, w_dp, b_dp, w_comp, b_comp, out, b, 0);
        }
    } else {
        // S3: zero d_out scratch; attention recomputes K/V per tile.
        bf16_t* AOr = (bf16_t*)d_ws;
        bf16_t* AOd = AOr + 73728;
        for (int b = 0; b < BATCH; ++b) {
            for (int H = 0; H < 2; ++H) {
                int n0 = H * NHALF;
                attn_rc_kernel<<<dim3(18, 8), dim3(64), 0, stream>>>(
                    rgb_fea, depth, w_exp, b_exp, w_rq, w_dk, w_dv, AOr, b, 0, n0);
                attn_rc_kernel<<<dim3(18, 8), dim3(64), 0, stream>>>(
                    rgb_fea, depth, w_exp, b_exp, w_dq, w_rk, w_rv, AOd, b, 1, n0);
                projcomp_kernel<<<dim3(18), dim3(256), 0, stream>>>(
                    AOr, AOd, w_rp, b_rp, w_dp, b_dp, w_comp, b_comp, out, b, n0);
            }
        }
    }
}

// Round 9
// 408.413 us; speedup vs baseline: 2.3415x; 1.9893x over previous
//
#include <hip/hip_runtime.h>
#include <math.h>

// R8: 812us. attn = 4 x 133us; Occupancy 11.7%, VALUBusy 23.8% -> grid-limited
// (288 blocks ~ 1.1/CU). Bank conflicts 465k from stride-8 LDS staging writes.
// R9: (a) single attn launch grid(36,8,4) = 1152 blocks via full K/V residence
// in ws (runtime ws_size gate, R8 path as fallback); (b) K/V LDS stride 12
// (48B) -> all 32 banks on b128 writes; (c) kv/projcomp batched launches.
#define BATCH 2
#define C 64
#define HH 48
#define WW 48
#define NTOK 2304
#define NHALF 1152
#define HEADS 8
#define KVSTRIDE 12   // floats per K/V LDS row (16B-aligned, conflict-free)

typedef unsigned short bf16_t;
__device__ __forceinline__ bf16_t f2bf(float f) {
    unsigned int u = __float_as_uint(f);
    u = (u + 0x7fffu + ((u >> 16) & 1u)) >> 16;   // RNE
    return (bf16_t)u;
}
__device__ __forceinline__ unsigned pack2(float a, float b) {
    return (unsigned)f2bf(a) | ((unsigned)f2bf(b) << 16);
}
__device__ __forceinline__ float4 ld_bf4(const bf16_t* p) {
    uint2 v = *(const uint2*)p;
    float4 r;
    r.x = __uint_as_float(v.x << 16); r.y = __uint_as_float(v.x & 0xffff0000u);
    r.z = __uint_as_float(v.y << 16); r.w = __uint_as_float(v.y & 0xffff0000u);
    return r;
}

// Stage one token-row of X (64 channels, subset c0::cstep) into LDS row.
// strm 0: rgb transpose gather. strm 1: conv1x1+ReLU+bilinear x2 (half-pixel;
// clamp == jax edge renormalization for 24->48).
__device__ __forceinline__ void stage_x_row(
    float* xrow, const float* rgb, const float* dep,
    const float* w_exp, const float* b_exp,
    int b, int n, int strm, int c0, int cstep)
{
    int wi = n / HH, hi = n % HH;
    if (strm == 0) {
        const float* base = rgb + (size_t)b * C * NTOK + (size_t)hi * WW + wi;
        for (int c = c0; c < 64; c += cstep)
            xrow[c] = base[(size_t)c * NTOK];
    } else {
        float cy = 0.5f * hi - 0.25f, cx = 0.5f * wi - 0.25f;
        float fy0 = floorf(cy), fx0 = floorf(cx);
        float fy = cy - fy0, fx = cx - fx0;
        int y0 = max((int)fy0, 0), x0 = max((int)fx0, 0);
        int y1 = min((int)fy0 + 1, 23), x1 = min((int)fx0 + 1, 23);
        const float* dp = dep + b * 576;
        float d00 = dp[y0*24 + x0], d01 = dp[y0*24 + x1];
        float d10 = dp[y1*24 + x0], d11 = dp[y1*24 + x1];
        for (int c = c0; c < 64; c += cstep) {
            float w = w_exp[c], bb = b_exp[c];
            float r00 = fmaxf(w*d00 + bb, 0.f), r01 = fmaxf(w*d01 + bb, 0.f);
            float r10 = fmaxf(w*d10 + bb, 0.f), r11 = fmaxf(w*d11 + bb, 0.f);
            xrow[c] = (1.f-fy)*((1.f-fx)*r00 + fx*r01) + fy*((1.f-fx)*r10 + fx*r11);
        }
    }
}

// ===========================================================================
// BIG PATH (ws >= 3,538,944 B): all K/V + AO resident in ws; 3 launches.
// ===========================================================================

// prep + one of {K,V} GEMM for one (b, strm). grid(36, 2, 4), 256 thr.
__global__ __launch_bounds__(256) void kv_all_kernel(
    const float* __restrict__ rgb, const float* __restrict__ dep,
    const float* __restrict__ w_exp, const float* __restrict__ b_exp,
    const float* __restrict__ w_rk, const float* __restrict__ w_rv,
    const float* __restrict__ w_dk, const float* __restrict__ w_dv,
    bf16_t* __restrict__ Kr, bf16_t* __restrict__ Vr,
    bf16_t* __restrict__ Kd, bf16_t* __restrict__ Vd)
{
    int tile = blockIdx.x;           // 0..35
    int m    = blockIdx.y;           // 0=K, 1=V
    int z    = blockIdx.z;           // b*2 + strm
    int b = z >> 1, strm = z & 1;
    const float* W = strm ? (m ? w_dv : w_dk) : (m ? w_rv : w_rk);
    bf16_t* O = (strm ? (m ? Vd : Kd) : (m ? Vr : Kr))
              + ((size_t)b * NTOK + tile * 64) * 64;

    __shared__ float Xs[64][68];
    __shared__ float Ws[64][68];
    int tid = threadIdx.x;
    {
        int r = tid & 63, c0 = tid >> 6;
        stage_x_row(&Xs[r][0], rgb, dep, w_exp, b_exp, b, tile*64 + r, strm, c0, 4);
    }
    int sr = tid >> 4, sc = (tid & 15) * 4;
    #pragma unroll
    for (int rr = 0; rr < 4; ++rr) {
        int r = rr*16 + sr;
        *(float4*)&Ws[r][sc] = *(const float4*)&W[r*64 + sc];
    }
    __syncthreads();

    int ty = tid >> 4, tx = tid & 15;
    float acc[4][4] = {};
    #pragma unroll
    for (int k = 0; k < 64; k += 4) {
        float4 xv[4], wv4[4];
        #pragma unroll
        for (int i = 0; i < 4; ++i) xv[i] = *(const float4*)&Xs[4*ty + i][k];
        #pragma unroll
        for (int j = 0; j < 4; ++j) wv4[j] = *(const float4*)&Ws[tx + 16*j][k];
        #pragma unroll
        for (int i = 0; i < 4; ++i)
            #pragma unroll
            for (int j = 0; j < 4; ++j)
                acc[i][j] += xv[i].x*wv4[j].x + xv[i].y*wv4[j].y + xv[i].z*wv4[j].z + xv[i].w*wv4[j].w;
    }
    #pragma unroll
    for (int i = 0; i < 4; ++i)
        #pragma unroll
        for (int j = 0; j < 4; ++j)
            O[(4*ty + i)*64 + tx + 16*j] = f2bf(acc[i][j]);
}

// split-K flash attention, all 4 (b,which) in one launch. grid(36, 8, 4),
// 256 thr (4 waves). Wave w owns keys [576w, 576w+576) in 9 x 64-key tiles
// staged to its own LDS quadrant (stride-12 rows). LDS partial merge (exact).
__global__ __launch_bounds__(256) void attn_all_kernel(
    const float* __restrict__ rgb, const float* __restrict__ dep,
    const float* __restrict__ w_exp, const float* __restrict__ b_exp,
    const float* __restrict__ w_rq, const float* __restrict__ w_dq,
    const bf16_t* __restrict__ Kr, const bf16_t* __restrict__ Vr,
    const bf16_t* __restrict__ Kd, const bf16_t* __restrict__ Vd,
    bf16_t* __restrict__ AOr, bf16_t* __restrict__ AOd)
{
    int qt = blockIdx.x;     // 0..35
    int h  = blockIdx.y;     // 0..7
    int z  = blockIdx.z;     // b*2 + which
    int b = z >> 1, which = z & 1;
    const float* wq = which ? w_dq : w_rq;
    const bf16_t* K = which ? Kr : Kd;
    const bf16_t* V = which ? Vr : Vd;
    bf16_t* AO      = which ? AOd : AOr;

    __shared__ float Xs[64][68];                        // X tile; reused for merge
    __shared__ float Wqs[8][64];
    __shared__ __align__(16) float Ks[4][64][KVSTRIDE]; // per-wave quadrants
    __shared__ __align__(16) float Vs[4][64][KVSTRIDE];

    int tid = threadIdx.x;
    int t = tid & 63;        // query lane
    int w = tid >> 6;        // wave id
    int n = qt * 64 + t;

    stage_x_row(&Xs[t][0], rgb, dep, w_exp, b_exp, b, n, which == 0 ? 0 : 1, w, 4);
    if (w == 0) {
        #pragma unroll
        for (int d = 0; d < 8; ++d) Wqs[d][t] = wq[(8*h + d)*64 + t];
    }
    __syncthreads();

    const float sc = 0.35355339059327373f * 1.4426950408889634f; // 8^-0.5*log2e
    float q[8];
    #pragma unroll
    for (int d = 0; d < 8; ++d) {
        float s = 0.f;
        #pragma unroll 8
        for (int c = 0; c < 64; ++c) s += Xs[t][c] * Wqs[d][c];
        q[d] = s * sc;
    }

    float mrun = -INFINITY, l = 0.f;
    float acc[8] = {};

    #pragma unroll 1
    for (int st = 0; st < 9; ++st) {
        __syncthreads();
        {
            size_t g = ((size_t)b * NTOK + (w*576 + st*64 + t)) * 64 + 8 * h;
            *(float4*)&Ks[w][t][0] = ld_bf4(&K[g]);
            *(float4*)&Ks[w][t][4] = ld_bf4(&K[g + 4]);
            *(float4*)&Vs[w][t][0] = ld_bf4(&V[g]);
            *(float4*)&Vs[w][t][4] = ld_bf4(&V[g + 4]);
        }
        __syncthreads();

        for (int g8 = 0; g8 < 8; ++g8) {
            float s[8];
            #pragma unroll
            for (int u = 0; u < 8; ++u) {
                const float4 ka = *(const float4*)&Ks[w][g8*8 + u][0];
                const float4 kb = *(const float4*)&Ks[w][g8*8 + u][4];
                s[u] = q[0]*ka.x + q[1]*ka.y + q[2]*ka.z + q[3]*ka.w
                     + q[4]*kb.x + q[5]*kb.y + q[6]*kb.z + q[7]*kb.w;
            }
            float tm = fmaxf(fmaxf(fmaxf(s[0],s[1]), fmaxf(s[2],s[3])),
                             fmaxf(fmaxf(s[4],s[5]), fmaxf(s[6],s[7])));
            float mn = fmaxf(mrun, tm);
            float alpha = __builtin_amdgcn_exp2f(mrun - mn);
            float ps = 0.f;
            #pragma unroll
            for (int u = 0; u < 8; ++u) { s[u] = __builtin_amdgcn_exp2f(s[u] - mn); ps += s[u]; }
            l = l * alpha + ps;
            #pragma unroll
            for (int d = 0; d < 8; ++d) acc[d] *= alpha;
            #pragma unroll
            for (int u = 0; u < 8; ++u) {
                const float4 va = *(const float4*)&Vs[w][g8*8 + u][0];
                const float4 vb = *(const float4*)&Vs[w][g8*8 + u][4];
                acc[0] += s[u]*va.x; acc[1] += s[u]*va.y; acc[2] += s[u]*va.z; acc[3] += s[u]*va.w;
                acc[4] += s[u]*vb.x; acc[5] += s[u]*vb.y; acc[6] += s[u]*vb.z; acc[7] += s[u]*vb.w;
            }
            mrun = mn;
        }
    }

    // exact flash merge of the 4 per-wave partials via Xs scratch
    float* part = &Xs[0][0];          // 4*64*10 = 2560 <= 4352 floats
    __syncthreads();
    {
        float* p = &part[(w*64 + t) * 10];
        p[0] = mrun; p[1] = l;
        #pragma unroll
        for (int d = 0; d < 8; ++d) p[2 + d] = acc[d];
    }
    __syncthreads();
    if (tid < 64) {
        float M = -INFINITY;
        #pragma unroll
        for (int v = 0; v < 4; ++v) M = fmaxf(M, part[(v*64 + t)*10]);
        float L = 0.f, o[8] = {};
        #pragma unroll
        for (int v = 0; v < 4; ++v) {
            const float* p = &part[(v*64 + t)*10];
            float al = __builtin_amdgcn_exp2f(p[0] - M);
            L += p[1] * al;
            #pragma unroll
            for (int d = 0; d < 8; ++d) o[d] += p[2 + d] * al;
        }
        float inv = 1.0f / L;
        uint4 ov;
        ov.x = pack2(o[0]*inv, o[1]*inv);
        ov.y = pack2(o[2]*inv, o[3]*inv);
        ov.z = pack2(o[4]*inv, o[5]*inv);
        ov.w = pack2(o[6]*inv, o[7]*inv);
        *(uint4*)&AO[((size_t)b * NTOK + n) * 64 + 8 * h] = ov;
    }
}

// fused proj -> compress -> GELU -> store, both batches. grid(36, 2), 256 thr.
__global__ __launch_bounds__(256) void projcomp_all_kernel(
    const bf16_t* __restrict__ AOr, const bf16_t* __restrict__ AOd,
    const float* __restrict__ w_rp, const float* __restrict__ b_rp,
    const float* __restrict__ w_dp, const float* __restrict__ b_dp,
    const float* __restrict__ w_comp, const float* __restrict__ b_comp,
    float* __restrict__ out)
{
    int tile = blockIdx.x;
    int b    = blockIdx.y;
    __shared__ float A[64][68];
    __shared__ float Bf[64][68];
    __shared__ float Pf[64][68];
    int tid = threadIdx.x;
    int sr = tid >> 4, sc = (tid & 15) * 4;
    int ty = tid >> 4, tx = tid & 15;
    float G[4][4] = {};

    #pragma unroll
    for (int half = 0; half < 2; ++half) {
        const bf16_t* AOx = half ? AOd : AOr;
        const float* Wp   = half ? w_dp : w_rp;
        const float* bp   = half ? b_dp : b_rp;
        #pragma unroll
        for (int rr = 0; rr < 4; ++rr) {
            int r = rr*16 + sr;
            *(float4*)&A[r][sc]  = ld_bf4(&AOx[((size_t)b*NTOK + tile*64 + r)*64 + sc]);
            *(float4*)&Bf[r][sc] = *(const float4*)&Wp[r*64 + sc];
        }
        __syncthreads();
        float acc[4][4] = {};
        #pragma unroll
        for (int k = 0; k < 64; k += 4) {
            float4 xv[4], wv[4];
            #pragma unroll
            for (int i = 0; i < 4; ++i) xv[i] = *(const float4*)&A[4*ty + i][k];
            #pragma unroll
            for (int j = 0; j < 4; ++j) wv[j] = *(const float4*)&Bf[tx + 16*j][k];
            #pragma unroll
            for (int i = 0; i < 4; ++i)
                #pragma unroll
                for (int j = 0; j < 4; ++j)
                    acc[i][j] += xv[i].x*wv[j].x + xv[i].y*wv[j].y + xv[i].z*wv[j].z + xv[i].w*wv[j].w;
        }
        __syncthreads();
        #pragma unroll
        for (int j = 0; j < 4; ++j) {
            float bj = bp[tx + 16*j];
            #pragma unroll
            for (int i = 0; i < 4; ++i)
                Pf[4*ty + i][tx + 16*j] = acc[i][j] + bj;
        }
        #pragma unroll
        for (int rr = 0; rr < 4; ++rr) {
            int r = rr*16 + sr;
            *(float4*)&Bf[r][sc] = *(const float4*)&w_comp[r*128 + half*64 + sc];
        }
        __syncthreads();
        #pragma unroll
        for (int k = 0; k < 64; k += 4) {
            float4 xv[4], wv[4];
            #pragma unroll
            for (int i = 0; i < 4; ++i) xv[i] = *(const float4*)&Pf[4*ty + i][k];
            #pragma unroll
            for (int j = 0; j < 4; ++j) wv[j] = *(const float4*)&Bf[tx + 16*j][k];
            #pragma unroll
            for (int i = 0; i < 4; ++i)
                #pragma unroll
                for (int j = 0; j < 4; ++j)
                    G[i][j] += xv[i].x*wv[j].x + xv[i].y*wv[j].y + xv[i].z*wv[j].z + xv[i].w*wv[j].w;
        }
        __syncthreads();
    }

    #pragma unroll
    for (int j = 0; j < 4; ++j) {
        int o = tx + 16*j;
        float bj = b_comp[o];
        #pragma unroll
        for (int i = 0; i < 4; ++i) {
            int n = tile*64 + 4*ty + i;
            int wi = n / HH, hi = n % HH;
            float x = G[i][j] + bj;
            float g = 0.5f * x * (1.0f + erff(x * 0.70710678118654752f));
            out[((b*C + o)*WW + wi)*HH + hi] = g;
        }
    }
}

// ===========================================================================
// FALLBACK PATHS (R8, proven): S1 (ws >= 589,824 B) and S3 (recompute).
// ===========================================================================
__global__ __launch_bounds__(256) void kv_kernel(
    const float* __restrict__ rgb, const float* __restrict__ dep,
    const float* __restrict__ w_exp, const float* __restrict__ b_exp,
    const float* __restrict__ wk, const float* __restrict__ wv,
    bf16_t* __restrict__ K, bf16_t* __restrict__ V, int b, int strm)
{
    int tile = blockIdx.x;
    int m    = blockIdx.y;
    const float* W = (m == 0) ? wk : wv;
    __shared__ float Xs[64][68];
    __shared__ float Ws[64][68];
    int tid = threadIdx.x;
    {
        int r = tid & 63, c0 = tid >> 6;
        stage_x_row(&Xs[r][0], rgb, dep, w_exp, b_exp, b, tile*64 + r, strm, c0, 4);
    }
    int sr = tid >> 4, sc = (tid & 15) * 4;
    #pragma unroll
    for (int rr = 0; rr < 4; ++rr) {
        int r = rr*16 + sr;
        *(float4*)&Ws[r][sc] = *(const float4*)&W[r*64 + sc];
    }
    __syncthreads();

    int ty = tid >> 4, tx = tid & 15;
    float acc[4][4] = {};
    #pragma unroll
    for (int k = 0; k < 64; k += 4) {
        float4 xv[4], wv4[4];
        #pragma unroll
        for (int i = 0; i < 4; ++i) xv[i] = *(const float4*)&Xs[4*ty + i][k];
        #pragma unroll
        for (int j = 0; j < 4; ++j) wv4[j] = *(const float4*)&Ws[tx + 16*j][k];
        #pragma unroll
        for (int i = 0; i < 4; ++i)
            #pragma unroll
            for (int j = 0; j < 4; ++j)
                acc[i][j] += xv[i].x*wv4[j].x + xv[i].y*wv4[j].y + xv[i].z*wv4[j].z + xv[i].w*wv4[j].w;
    }
    bf16_t* O = (m == 0 ? K : V) + (size_t)tile * 4096;
    #pragma unroll
    for (int i = 0; i < 4; ++i)
        #pragma unroll
        for (int j = 0; j < 4; ++j)
            O[(4*ty + i)*64 + tx + 16*j] = f2bf(acc[i][j]);
}

__global__ __launch_bounds__(256) void attn_kv_kernel(
    const float* __restrict__ rgb, const float* __restrict__ dep,
    const float* __restrict__ w_exp, const float* __restrict__ b_exp,
    const float* __restrict__ wq,
    const bf16_t* __restrict__ K, const bf16_t* __restrict__ V,
    bf16_t* __restrict__ AO, int b, int which)
{
    int qt = blockIdx.x;
    int h  = blockIdx.y;
    __shared__ float Xs[64][68];
    __shared__ float Wqs[8][64];
    __shared__ __align__(16) float Ks[4][64][KVSTRIDE];
    __shared__ __align__(16) float Vs[4][64][KVSTRIDE];

    int tid = threadIdx.x;
    int t = tid & 63;
    int w = tid >> 6;
    int n = qt * 64 + t;

    stage_x_row(&Xs[t][0], rgb, dep, w_exp, b_exp, b, n, which == 0 ? 0 : 1, w, 4);
    if (w == 0) {
        #pragma unroll
        for (int d = 0; d < 8; ++d) Wqs[d][t] = wq[(8*h + d)*64 + t];
    }
    __syncthreads();

    const float sc = 0.35355339059327373f * 1.4426950408889634f;
    float q[8];
    #pragma unroll
    for (int d = 0; d < 8; ++d) {
        float s = 0.f;
        #pragma unroll 8
        for (int c = 0; c < 64; ++c) s += Xs[t][c] * Wqs[d][c];
        q[d] = s * sc;
    }

    float mrun = -INFINITY, l = 0.f;
    float acc[8] = {};

    #pragma unroll 1
    for (int st = 0; st < 9; ++st) {
        __syncthreads();
        {
            int g = (w*576 + st*64 + t) * 64 + 8 * h;
            *(float4*)&Ks[w][t][0] = ld_bf4(&K[g]);
            *(float4*)&Ks[w][t][4] = ld_bf4(&K[g + 4]);
            *(float4*)&Vs[w][t][0] = ld_bf4(&V[g]);
            *(float4*)&Vs[w][t][4] = ld_bf4(&V[g + 4]);
        }
        __syncthreads();

        for (int g8 = 0; g8 < 8; ++g8) {
            float s[8];
            #pragma unroll
            for (int u = 0; u < 8; ++u) {
                const float4 ka = *(const float4*)&Ks[w][g8*8 + u][0];
                const float4 kb = *(const float4*)&Ks[w][g8*8 + u][4];
                s[u] = q[0]*ka.x + q[1]*ka.y + q[2]*ka.z + q[3]*ka.w
                     + q[4]*kb.x + q[5]*kb.y + q[6]*kb.z + q[7]*kb.w;
            }
            float tm = fmaxf(fmaxf(fmaxf(s[0],s[1]), fmaxf(s[2],s[3])),
                             fmaxf(fmaxf(s[4],s[5]), fmaxf(s[6],s[7])));
            float mn = fmaxf(mrun, tm);
            float alpha = __builtin_amdgcn_exp2f(mrun - mn);
            float ps = 0.f;
            #pragma unroll
            for (int u = 0; u < 8; ++u) { s[u] = __builtin_amdgcn_exp2f(s[u] - mn); ps += s[u]; }
            l = l * alpha + ps;
            #pragma unroll
            for (int d = 0; d < 8; ++d) acc[d] *= alpha;
            #pragma unroll
            for (int u = 0; u < 8; ++u) {
                const float4 va = *(const float4*)&Vs[w][g8*8 + u][0];
                const float4 vb = *(const float4*)&Vs[w][g8*8 + u][4];
                acc[0] += s[u]*va.x; acc[1] += s[u]*va.y; acc[2] += s[u]*va.z; acc[3] += s[u]*va.w;
                acc[4] += s[u]*vb.x; acc[5] += s[u]*vb.y; acc[6] += s[u]*vb.z; acc[7] += s[u]*vb.w;
            }
            mrun = mn;
        }
    }

    float* part = &Xs[0][0];
    __syncthreads();
    {
        float* p = &part[(w*64 + t) * 10];
        p[0] = mrun; p[1] = l;
        #pragma unroll
        for (int d = 0; d < 8; ++d) p[2 + d] = acc[d];
    }
    __syncthreads();
    if (tid < 64) {
        float M = -INFINITY;
        #pragma unroll
        for (int v = 0; v < 4; ++v) M = fmaxf(M, part[(v*64 + t)*10]);
        float L = 0.f, o[8] = {};
        #pragma unroll
        for (int v = 0; v < 4; ++v) {
            const float* p = &part[(v*64 + t)*10];
            float al = __builtin_amdgcn_exp2f(p[0] - M);
            L += p[1] * al;
            #pragma unroll
            for (int d = 0; d < 8; ++d) o[d] += p[2 + d] * al;
        }
        float inv = 1.0f / L;
        uint4 ov;
        ov.x = pack2(o[0]*inv, o[1]*inv);
        ov.y = pack2(o[2]*inv, o[3]*inv);
        ov.z = pack2(o[4]*inv, o[5]*inv);
        ov.w = pack2(o[6]*inv, o[7]*inv);
        *(uint4*)&AO[(size_t)n * 64 + 8 * h] = ov;
    }
}

__global__ __launch_bounds__(64) void attn_rc_kernel(
    const float* __restrict__ rgb, const float* __restrict__ dep,
    const float* __restrict__ w_exp, const float* __restrict__ b_exp,
    const float* __restrict__ wq, const float* __restrict__ wk, const float* __restrict__ wv,
    bf16_t* __restrict__ AO, int b, int which, int n0)
{
    int qt = blockIdx.x;
    int h  = blockIdx.y;
    __shared__ float X[64][68];
    __shared__ float Wq8[8][64], Wk8[8][64], Wv8[8][64];
    __shared__ __align__(16) float Kt[64][8];
    __shared__ __align__(16) float Vt[64][8];

    int t = threadIdx.x;
    int qstrm = (which == 0) ? 0 : 1;
    int kstrm = 1 - qstrm;
    #pragma unroll
    for (int d = 0; d < 8; ++d) {
        Wq8[d][t] = wq[(8*h + d)*64 + t];
        Wk8[d][t] = wk[(8*h + d)*64 + t];
        Wv8[d][t] = wv[(8*h + d)*64 + t];
    }
    int n = n0 + qt * 64 + t;
    stage_x_row(&X[t][0], rgb, dep, w_exp, b_exp, b, n, qstrm, 0, 1);
    __syncthreads();

    const float sc = 0.35355339059327373f * 1.4426950408889634f;
    float q[8];
    #pragma unroll
    for (int d = 0; d < 8; ++d) {
        float s = 0.f;
        #pragma unroll 8
        for (int c = 0; c < 64; ++c) s += X[t][c] * Wq8[d][c];
        q[d] = s * sc;
    }

    float mrun = -INFINITY, l = 0.f;
    float acc[8] = {};

    for (int kt = 0; kt < 36; ++kt) {
        __syncthreads();
        stage_x_row(&X[t][0], rgb, dep, w_exp, b_exp, b, kt*64 + t, kstrm, 0, 1);
        #pragma unroll
        for (int d = 0; d < 8; ++d) {
            float kk = 0.f, vv = 0.f;
            #pragma unroll 8
            for (int c = 0; c < 64; ++c) {
                float x = X[t][c];
                kk += x * Wk8[d][c];
                vv += x * Wv8[d][c];
            }
            Kt[t][d] = kk;
            Vt[t][d] = vv;
        }
        __syncthreads();

        for (int g8 = 0; g8 < 8; ++g8) {
            float s[8];
            #pragma unroll
            for (int u = 0; u < 8; ++u) {
                const float4 ka = *(const float4*)&Kt[g8*8 + u][0];
                const float4 kb = *(const float4*)&Kt[g8*8 + u][4];
                s[u] = q[0]*ka.x + q[1]*ka.y + q[2]*ka.z + q[3]*ka.w
                     + q[4]*kb.x + q[5]*kb.y + q[6]*kb.z + q[7]*kb.w;
            }
            float tm = fmaxf(fmaxf(fmaxf(s[0],s[1]), fmaxf(s[2],s[3])),
                             fmaxf(fmaxf(s[4],s[5]), fmaxf(s[6],s[7])));
            float mn = fmaxf(mrun, tm);
            float alpha = __builtin_amdgcn_exp2f(mrun - mn);
            float ps = 0.f;
            #pragma unroll
            for (int u = 0; u < 8; ++u) { s[u] = __builtin_amdgcn_exp2f(s[u] - mn); ps += s[u]; }
            l = l * alpha + ps;
            #pragma unroll
            for (int d = 0; d < 8; ++d) acc[d] *= alpha;
            #pragma unroll
            for (int u = 0; u < 8; ++u) {
                const float4 va = *(const float4*)&Vt[g8*8 + u][0];
                const float4 vb = *(const float4*)&Vt[g8*8 + u][4];
                acc[0] += s[u]*va.x; acc[1] += s[u]*va.y; acc[2] += s[u]*va.z; acc[3] += s[u]*va.w;
                acc[4] += s[u]*vb.x; acc[5] += s[u]*vb.y; acc[6] += s[u]*vb.z; acc[7] += s[u]*vb.w;
            }
            mrun = mn;
        }
    }
    float inv = 1.0f / l;
    uint4 o;
    o.x = pack2(acc[0]*inv, acc[1]*inv);
    o.y = pack2(acc[2]*inv, acc[3]*inv);
    o.z = pack2(acc[4]*inv, acc[5]*inv);
    o.w = pack2(acc[6]*inv, acc[7]*inv);
    *(uint4*)&AO[(size_t)(n - n0) * 64 + 8 * h] = o;
}

__global__ __launch_bounds__(256) void projcomp_kernel(
    const bf16_t* __restrict__ AOr, const bf16_t* __restrict__ AOd,
    const float* __restrict__ w_rp, const float* __restrict__ b_rp,
    const float* __restrict__ w_dp, const float* __restrict__ b_dp,
    const float* __restrict__ w_comp, const float* __restrict__ b_comp,
    float* __restrict__ out, int b, int n0)
{
    int tile = blockIdx.x;
    __shared__ float A[64][68];
    __shared__ float Bf[64][68];
    __shared__ float Pf[64][68];
    int tid = threadIdx.x;
    int sr = tid >> 4, sc = (tid & 15) * 4;
    int ty = tid >> 4, tx = tid & 15;
    float G[4][4] = {};

    #pragma unroll
    for (int half = 0; half < 2; ++half) {
        const bf16_t* AOx = half ? AOd : AOr;
        const float* Wp   = half ? w_dp : w_rp;
        const float* bp   = half ? b_dp : b_rp;
        #pragma unroll
        for (int rr = 0; rr < 4; ++rr) {
            int r = rr*16 + sr;
            *(float4*)&A[r][sc]  = ld_bf4(&AOx[((size_t)tile*64 + r)*64 + sc]);
            *(float4*)&Bf[r][sc] = *(const float4*)&Wp[r*64 + sc];
        }
        __syncthreads();
        float acc[4][4] = {};
        #pragma unroll
        for (int k = 0; k < 64; k += 4) {
            float4 xv[4], wv[4];
            #pragma unroll
            for (int i = 0; i < 4; ++i) xv[i] = *(const float4*)&A[4*ty + i][k];
            #pragma unroll
            for (int j = 0; j < 4; ++j) wv[j] = *(const float4*)&Bf[tx + 16*j][k];
            #pragma unroll
            for (int i = 0; i < 4; ++i)
                #pragma unroll
                for (int j = 0; j < 4; ++j)
                    acc[i][j] += xv[i].x*wv[j].x + xv[i].y*wv[j].y + xv[i].z*wv[j].z + xv[i].w*wv[j].w;
        }
        __syncthreads();
        #pragma unroll
        for (int j = 0; j < 4; ++j) {
            float bj = bp[tx + 16*j];
            #pragma unroll
            for (int i = 0; i < 4; ++i)
                Pf[4*ty + i][tx + 16*j] = acc[i][j] + bj;
        }
        #pragma unroll
        for (int rr = 0; rr < 4; ++rr) {
            int r = rr*16 + sr;
            *(float4*)&Bf[r][sc] = *(const float4*)&w_comp[r*128 + half*64 + sc];
        }
        __syncthreads();
        #pragma unroll
        for (int k = 0; k < 64; k += 4) {
            float4 xv[4], wv[4];
            #pragma unroll
            for (int i = 0; i < 4; ++i) xv[i] = *(const float4*)&Pf[4*ty + i][k];
            #pragma unroll
            for (int j = 0; j < 4; ++j) wv[j] = *(const float4*)&Bf[tx + 16*j][k];
            #pragma unroll
            for (int i = 0; i < 4; ++i)
                #pragma unroll
                for (int j = 0; j < 4; ++j)
                    G[i][j] += xv[i].x*wv[j].x + xv[i].y*wv[j].y + xv[i].z*wv[j].z + xv[i].w*wv[j].w;
        }
        __syncthreads();
    }

    #pragma unroll
    for (int j = 0; j < 4; ++j) {
        int o = tx + 16*j;
        float bj = b_comp[o];
        #pragma unroll
        for (int i = 0; i < 4; ++i) {
            int n = n0 + tile*64 + 4*ty + i;
            int wi = n / HH, hi = n % HH;
            float x = G[i][j] + bj;
            float g = 0.5f * x * (1.0f + erff(x * 0.70710678118654752f));
            out[((b*C + o)*WW + wi)*HH + hi] = g;
        }
    }
}

// ---------------------------------------------------------------------------
extern "C" void kernel_launch(void* const* d_in, const int* in_sizes, int n_in,
                              void* d_out, int out_size, void* d_ws, size_t ws_size,
                              hipStream_t stream) {
    const float* rgb_fea = (const float*)d_in[0];
    const float* depth   = (const float*)d_in[1];
    const float* w_exp   = (const float*)d_in[2];
    const float* b_exp   = (const float*)d_in[3];
    const float* w_rq    = (const float*)d_in[4];
    const float* w_rk    = (const float*)d_in[5];
    const float* w_rv    = (const float*)d_in[6];
    const float* w_dq    = (const float*)d_in[7];
    const float* w_dk    = (const float*)d_in[8];
    const float* w_dv    = (const float*)d_in[9];
    const float* w_rp    = (const float*)d_in[10];
    const float* b_rp    = (const float*)d_in[11];
    const float* w_dp    = (const float*)d_in[12];
    const float* b_dp    = (const float*)d_in[13];
    const float* w_comp  = (const float*)d_in[14];
    const float* b_comp  = (const float*)d_in[15];
    float* out = (float*)d_out;

    const size_t BUF = (size_t)BATCH * NTOK * 64;   // bf16 elems per buffer

    if (ws_size >= 6 * BUF * sizeof(bf16_t)) {
        // BIG: Kr,Vr,Kd,Vd,AOr,AOd all in ws (3,538,944 B). 3 launches.
        bf16_t* Kr  = (bf16_t*)d_ws;
        bf16_t* Vr  = Kr + BUF;
        bf16_t* Kd  = Vr + BUF;
        bf16_t* Vd  = Kd + BUF;
        bf16_t* AOr = Vd + BUF;
        bf16_t* AOd = AOr + BUF;
        kv_all_kernel<<<dim3(36, 2, 4), dim3(256), 0, stream>>>(
            rgb_fea, depth, w_exp, b_exp, w_rk, w_rv, w_dk, w_dv, Kr, Vr, Kd, Vd);
        attn_all_kernel<<<dim3(36, 8, 4), dim3(256), 0, stream>>>(
            rgb_fea, depth, w_exp, b_exp, w_rq, w_dq, Kr, Vr, Kd, Vd, AOr, AOd);
        projcomp_all_kernel<<<dim3(36, 2), dim3(256), 0, stream>>>(
            AOr, AOd, w_rp, b_rp, w_dp, b_dp, w_comp, b_comp, out);
    } else if (ws_size >= 589824) {
        // S1 (R8 proven): K/V in d_out high half, AO in ws.
        bf16_t* Kb  = (bf16_t*)((float*)d_out + 147456);
        bf16_t* Vb  = Kb + 147456;
        bf16_t* AOr = (bf16_t*)d_ws;
        bf16_t* AOd = AOr + 147456;
        for (int b = 0; b < BATCH; ++b) {
            kv_kernel<<<dim3(36, 2), dim3(256), 0, stream>>>(
                rgb_fea, depth, w_exp, b_exp, w_dk, w_dv, Kb, Vb, b, 1);
            attn_kv_kernel<<<dim3(36, 8), dim3(256), 0, stream>>>(
                rgb_fea, depth, w_exp, b_exp, w_rq, Kb, Vb, AOr, b, 0);
            kv_kernel<<<dim3(36, 2), dim3(256), 0, stream>>>(
                rgb_fea, depth, w_exp, b_exp, w_rk, w_rv, Kb, Vb, b, 0);
            attn_kv_kernel<<<dim3(36, 8), dim3(256), 0, stream>>>(
                rgb_fea, depth, w_exp, b_exp, w_dq, Kb, Vb, AOd, b, 1);
            projcomp_kernel<<<dim3(36), dim3(256), 0, stream>>>(
                AOr, AOd, w_rp, b_rp, w_dp, b_dp, w_comp, b_comp, out, b, 0);
        }
    } else {
        // S3: zero d_out scratch; attention recomputes K/V per tile.
        bf16_t* AOr = (bf16_t*)d_ws;
        bf16_t* AOd = AOr + 73728;
        for (int b = 0; b < BATCH; ++b) {
            for (int H = 0; H < 2; ++H) {
                int n0 = H * NHALF;
                attn_rc_kernel<<<dim3(18, 8), dim3(64), 0, stream>>>(
                    rgb_fea, depth, w_exp, b_exp, w_rq, w_dk, w_dv, AOr, b, 0, n0);
                attn_rc_kernel<<<dim3(18, 8), dim3(64), 0, stream>>>(
                    rgb_fea, depth, w_exp, b_exp, w_dq, w_rk, w_rv, AOd, b, 1, n0);
                projcomp_kernel<<<dim3(18), dim3(256), 0, stream>>>(
                    AOr, AOd, w_rp, b_rp, w_dp, b_dp, w_comp, b_comp, out, b, n0);
            }
        }
    }
}